// Round 4
// baseline (156.558 us; speedup 1.0000x reference)
//
#include <hip/hip_runtime.h>

// SATD loss: sum(|H8 @ (orig - pred)|) over [524288, 3, 8, 8] fp32 blocks.
// Memory-bound streaming: 805 MB read -> 1 scalar. R3 established that access
// pattern (strided vs contiguous) doesn't move BW (~5.5 TB/s). This round:
// persistent grid (2048 blocks = 8/CU, single dispatch pass), block-contiguous
// chunks, unroll 8 (16 loads in flight per thread), plain loads (no nt).
//
// FWHT-8 distributed across lanes: a wave's 64 float4s = 4 whole 8x8 blocks;
// rows of a block live in lane bits 1..3, so the row-transform is 3 shfl_xor
// butterfly stages. abs-sum is invariant to output order, matching the ref.

typedef float fvec4 __attribute__((ext_vector_type(4)));

__global__ __launch_bounds__(256) void satd_loss_kernel(
        const fvec4* __restrict__ orig, const fvec4* __restrict__ pred,
        float* __restrict__ out, int n4) {
    const int per_block = n4 / gridDim.x;            // 12288 float4s per block
    const int base = blockIdx.x * per_block + threadIdx.x;
    const int lane = threadIdx.x & 63;

    float acc = 0.0f;

    // per_block = 48 * 256; unroll 8 -> 6 groups
    for (int k0 = 0; k0 < per_block; k0 += 8 * 256) {
        fvec4 d[8];
        #pragma unroll
        for (int k = 0; k < 8; ++k) {
            const int idx = base + k0 + k * 256;
            fvec4 a = orig[idx];
            fvec4 b = pred[idx];
            d[k] = a - b;
        }

        #pragma unroll
        for (int k = 0; k < 8; ++k) {
            fvec4 t = d[k];
            // distributed FWHT-8: rows live in lane bits 1..3
            #pragma unroll
            for (int m = 2; m <= 8; m <<= 1) {
                const bool hi = (lane & m) != 0;
                fvec4 p;
                p.x = __shfl_xor(t.x, m, 64);
                p.y = __shfl_xor(t.y, m, 64);
                p.z = __shfl_xor(t.z, m, 64);
                p.w = __shfl_xor(t.w, m, 64);
                fvec4 add = t + p;
                fvec4 sub = p - t;
                t = hi ? sub : add;
            }
            acc += fabsf(t.x) + fabsf(t.y) + fabsf(t.z) + fabsf(t.w);
        }
    }

    // wave-64 reduction
    #pragma unroll
    for (int off = 32; off > 0; off >>= 1)
        acc += __shfl_down(acc, off, 64);

    __shared__ float wsum[4];
    const int wid = threadIdx.x >> 6;
    if (lane == 0) wsum[wid] = acc;
    __syncthreads();

    if (threadIdx.x == 0) {
        float s = wsum[0] + wsum[1] + wsum[2] + wsum[3];
        atomicAdd(out, s);
    }
}

extern "C" void kernel_launch(void* const* d_in, const int* in_sizes, int n_in,
                              void* d_out, int out_size, void* d_ws, size_t ws_size,
                              hipStream_t stream) {
    const fvec4* orig = (const fvec4*)d_in[0];
    const fvec4* pred = (const fvec4*)d_in[1];
    float* out = (float*)d_out;

    const int nelem = in_sizes[0];   // 524288*3*64 = 100663296 floats
    const int n4 = nelem / 4;        // 25165824 float4s = 2048 * 12288

    // harness poisons d_out; zero it every call (graph-capturable memset node)
    (void)hipMemsetAsync(out, 0, sizeof(float) * (size_t)out_size, stream);

    const int block = 256;
    const int grid = 2048;           // 8 blocks/CU x 256 CU: persistent, 1 pass

    satd_loss_kernel<<<grid, block, 0, stream>>>(orig, pred, out, n4);
}